// Round 2
// baseline (743.951 us; speedup 1.0000x reference)
//
#include <hip/hip_runtime.h>

#define B_   64
#define L_   512
#define D_   768
#define NF_  100
#define W_   768
#define KT_  868          // D_ + NF_
#define TOK_ 3
#define CLS_ 2
#define MTOT_ (B_ * L_)   // 32768

// ---------------- tag init: tag[m][t] = b2[t] (atomic accumulate target) --------
__global__ void init_tag_kernel(float* __restrict__ tag, const float* __restrict__ b2) {
    int i = blockIdx.x * blockDim.x + threadIdx.x;
    if (i < MTOT_ * TOK_) tag[i] = b2[i % TOK_];
}

// ---------------- cls head: cls_logits = seq[:,0,:] @ cls_w + cls_b ------------
__global__ void cls_kernel(const float* __restrict__ seq, const float* __restrict__ cls_w,
                           const float* __restrict__ cls_b, float* __restrict__ out) {
    int b = blockIdx.x;
    int t = threadIdx.x; // 64 threads = 1 wave
    const float* row = seq + (size_t)b * L_ * D_;
    float a0 = 0.f, a1 = 0.f;
    for (int d = t; d < D_; d += 64) {
        float x = row[d];
        a0 += x * cls_w[d * CLS_ + 0];
        a1 += x * cls_w[d * CLS_ + 1];
    }
    for (int off = 32; off; off >>= 1) {
        a0 += __shfl_down(a0, off);
        a1 += __shfl_down(a1, off);
    }
    if (t == 0) {
        out[b * CLS_ + 0] = a0 + cls_b[0];
        out[b * CLS_ + 1] = a1 + cls_b[1];
    }
}

// ---------------- valid compaction: gidx[b][p] = source l of p-th valid token --
__global__ void compact_kernel(const int* __restrict__ valid, int* __restrict__ gidx) {
    __shared__ int s[L_];
    int b = blockIdx.x, t = threadIdx.x; // 512 threads
    int v = valid[b * L_ + t];
    s[t] = v;
    __syncthreads();
    // Hillis-Steele inclusive scan
    for (int off = 1; off < L_; off <<= 1) {
        int x = (t >= off) ? s[t - off] : 0;
        __syncthreads();
        s[t] += x;
        __syncthreads();
    }
    int inc = s[t];
    gidx[b * L_ + t] = -1;
    __syncthreads();
    if (v) gidx[b * L_ + inc - 1] = t;
}

// ---------------- enrichment: enr = relu(feat @ enr_w + enr_b) -----------------
// 32 rows/block, 128 threads: thread = (row = tid>>2, colgroup q = tid&3 -> 25 cols)
__global__ void enrich_kernel(const float* __restrict__ feat,
                              const float* __restrict__ ew,
                              const float* __restrict__ eb,
                              float* __restrict__ enr) {
    __shared__ float sw[NF_ * NF_];   // 40 KB
    __shared__ float sf[32][NF_];     // 12.8 KB
    __shared__ float sb[NF_];
    const int tid = threadIdx.x;
    const int row0 = blockIdx.x * 32;
    for (int i = tid; i < NF_ * NF_; i += 128) sw[i] = ew[i];
    for (int i = tid; i < 32 * NF_; i += 128) sf[i / NF_][i % NF_] = feat[(size_t)row0 * NF_ + i];
    if (tid < NF_) sb[tid] = eb[tid];
    __syncthreads();
    const int r = tid >> 2;
    const int q = tid & 3;
    float acc[25];
#pragma unroll
    for (int j = 0; j < 25; ++j) acc[j] = 0.f;
    for (int g = 0; g < NF_; ++g) {
        float f = sf[r][g];
        const float* wr = &sw[g * NF_ + q * 25];
#pragma unroll
        for (int j = 0; j < 25; ++j) acc[j] += f * wr[j];
    }
    float* orow = enr + (size_t)(row0 + r) * NF_ + q * 25;
#pragma unroll
    for (int j = 0; j < 25; ++j) {
        float v = acc[j] + sb[q * 25 + j];
        orow[j] = v > 0.f ? v : 0.f;
    }
}

// ---------------- main GEMM + fused tag head -----------------------------------
// A (32768 x 868): k<768 -> gathered seq rows (zero when gidx<0); k>=768 -> enr
// B = w1 (868 x 768). h = relu(A@B + b1); tag += h @ w2 (atomic, 6 partials/row)
#define BM 64
#define BN 128
#define BK 16
#define AST 68   // As row stride: 16B-aligned float4, conflict-free staging

__global__ __launch_bounds__(256)
void main_gemm(const float* __restrict__ seq,
               const int* __restrict__ gidx,
               const float* __restrict__ enr,
               const float* __restrict__ w1,
               const float* __restrict__ b1,
               const float* __restrict__ w2,
               float* __restrict__ tag) {
    __shared__ float As[BK * AST];     // As[k][m]
    __shared__ float Bs[BK][BN];       // Bs[k][n]
    __shared__ float sw2[BN][TOK_];

    const int tid = threadIdx.x;
    const int tx = tid & 15;   // cols tx*8 .. tx*8+7
    const int ty = tid >> 4;   // rows ty*4 .. ty*4+3
    const int n0 = blockIdx.x * BN;
    const int row0 = blockIdx.y * BM;

    for (int i = tid; i < BN * TOK_; i += 256) {
        int n = i / TOK_;
        sw2[n][i - n * TOK_] = w2[(size_t)(n0 + n) * TOK_ + (i - n * TOK_)];
    }

    // A staging: thread loads (k = tid&15, rows m0+16*i)
    const int ks = tid & 15;
    const int m0 = tid >> 4;
    const float* abase[4];
    float amul[4];
    const float* ebase[4];
#pragma unroll
    for (int i = 0; i < 4; ++i) {
        int row = row0 + m0 + 16 * i;
        int b = row >> 9;               // /L_
        int g = gidx[row];
        amul[i] = (g >= 0) ? 1.f : 0.f;
        int gs = (g >= 0) ? g : 0;
        abase[i] = seq + ((size_t)b * L_ + gs) * D_;
        ebase[i] = enr + (size_t)row * NF_;
    }

    // B staging: thread loads (n = tid&127, k = (tid>>7) + 2*i)
    const int nB = tid & 127;
    const int kB = tid >> 7;

    float acc[4][8];
#pragma unroll
    for (int i = 0; i < 4; ++i)
#pragma unroll
        for (int j = 0; j < 8; ++j) acc[i][j] = 0.f;

    const int KTILES = (KT_ + BK - 1) / BK;  // 55
    for (int kt = 0; kt < KTILES; ++kt) {
        const int k0 = kt * BK;
        __syncthreads();
        if (k0 < D_) {                      // uniform branch: seq half
#pragma unroll
            for (int i = 0; i < 4; ++i)
                As[ks * AST + m0 + 16 * i] = amul[i] * abase[i][k0 + ks];
        } else {                            // enriched half (+ K tail guard)
            const int kk = k0 + ks - D_;
            const bool ok = (k0 + ks) < KT_;
#pragma unroll
            for (int i = 0; i < 4; ++i)
                As[ks * AST + m0 + 16 * i] = ok ? ebase[i][kk] : 0.f;
        }
#pragma unroll
        for (int i = 0; i < 8; ++i) {
            int k = k0 + kB + 2 * i;
            Bs[kB + 2 * i][nB] = (k < KT_) ? w1[(size_t)k * W_ + n0 + nB] : 0.f;
        }
        __syncthreads();
#pragma unroll
        for (int k = 0; k < BK; ++k) {
            float4 a  = *(const float4*)&As[k * AST + ty * 4];
            float4 b0 = *(const float4*)&Bs[k][tx * 8];
            float4 b1v = *(const float4*)&Bs[k][tx * 8 + 4];
            float av[4] = {a.x, a.y, a.z, a.w};
            float bv[8] = {b0.x, b0.y, b0.z, b0.w, b1v.x, b1v.y, b1v.z, b1v.w};
#pragma unroll
            for (int i = 0; i < 4; ++i)
#pragma unroll
                for (int j = 0; j < 8; ++j)
                    acc[i][j] += av[i] * bv[j];
        }
    }

    // epilogue: bias + relu + partial tag = h @ w2 (reduce over this block's 128 n's)
    float4 bb0 = *(const float4*)&b1[n0 + tx * 8];
    float4 bb1 = *(const float4*)&b1[n0 + tx * 8 + 4];
    float bbv[8] = {bb0.x, bb0.y, bb0.z, bb0.w, bb1.x, bb1.y, bb1.z, bb1.w};
    float tp[4][TOK_];
#pragma unroll
    for (int i = 0; i < 4; ++i)
#pragma unroll
        for (int t = 0; t < TOK_; ++t) tp[i][t] = 0.f;
#pragma unroll
    for (int i = 0; i < 4; ++i) {
#pragma unroll
        for (int j = 0; j < 8; ++j) {
            float h = acc[i][j] + bbv[j];
            h = h > 0.f ? h : 0.f;
            int n = tx * 8 + j;
#pragma unroll
            for (int t = 0; t < TOK_; ++t) tp[i][t] += h * sw2[n][t];
        }
    }
    // reduce across the 16 tx lanes (same wave, width-16 groups)
#pragma unroll
    for (int off = 8; off; off >>= 1)
#pragma unroll
        for (int i = 0; i < 4; ++i)
#pragma unroll
            for (int t = 0; t < TOK_; ++t)
                tp[i][t] += __shfl_down(tp[i][t], off, 16);
    if (tx == 0) {
#pragma unroll
        for (int i = 0; i < 4; ++i) {
            int row = row0 + ty * 4 + i;
#pragma unroll
            for (int t = 0; t < TOK_; ++t)
                atomicAdd(&tag[(size_t)row * TOK_ + t], tp[i][t]);
        }
    }
}

extern "C" void kernel_launch(void* const* d_in, const int* in_sizes, int n_in,
                              void* d_out, int out_size, void* d_ws, size_t ws_size,
                              hipStream_t stream) {
    const float* seq   = (const float*)d_in[0];
    const float* feat  = (const float*)d_in[1];
    const int*   valid = (const int*)d_in[2];
    const float* enr_w = (const float*)d_in[3];
    const float* enr_b = (const float*)d_in[4];
    const float* w1    = (const float*)d_in[5];
    const float* b1    = (const float*)d_in[6];
    const float* w2    = (const float*)d_in[7];
    const float* b2    = (const float*)d_in[8];
    const float* cls_w = (const float*)d_in[9];
    const float* cls_b = (const float*)d_in[10];

    float* out = (float*)d_out;
    float* cls_out = out;                 // 64*2 floats, first in return order
    float* tag_out = out + B_ * CLS_;     // 32768*3 floats

    int*   gidx = (int*)d_ws;                                       // 128 KB
    float* enr  = (float*)((char*)d_ws + (size_t)MTOT_ * sizeof(int)); // 12.8 MB

    init_tag_kernel<<<(MTOT_ * TOK_ + 255) / 256, 256, 0, stream>>>(tag_out, b2);
    cls_kernel<<<B_, 64, 0, stream>>>(seq, cls_w, cls_b, cls_out);
    compact_kernel<<<B_, L_, 0, stream>>>(valid, gidx);
    enrich_kernel<<<MTOT_ / 32, 128, 0, stream>>>(feat, enr_w, enr_b, enr);
    dim3 grid(W_ / BN, MTOT_ / BM);
    main_gemm<<<grid, 256, 0, stream>>>(seq, gidx, enr, w1, b1, w2, tag_out);
}

// Round 3
// 298.667 us; speedup vs baseline: 2.4909x; 2.4909x over previous
//
#include <hip/hip_runtime.h>

#define B_    64
#define L_    512
#define D_    768
#define NF_   100
#define W_    768
#define TOK_  3
#define CLS_  2
#define MTOT_ (B_ * L_)   // 32768
#define KP_   896         // padded K for main GEMM (768 seq + 128 padded enr)
#define NFP_  128         // padded NF

typedef __attribute__((ext_vector_type(8))) short  bf16x8;
typedef __attribute__((ext_vector_type(4))) float  f32x4;

__device__ __forceinline__ unsigned short f2bf(float f) {
    union { float f; unsigned int u; } v; v.f = f;
    unsigned int u = v.u;
    u += 0x7fffu + ((u >> 16) & 1u);   // round-to-nearest-even
    return (unsigned short)(u >> 16);
}

typedef __attribute__((address_space(3))) unsigned int        lds_uint;
typedef const __attribute__((address_space(1))) unsigned int  gbl_uint;

__device__ __forceinline__ void gload_lds16(const void* gp, void* lp) {
    // 16B per lane, LDS dest = wave-uniform base + lane*16
    __builtin_amdgcn_global_load_lds((gbl_uint*)gp, (lds_uint*)lp, 16, 0, 0);
}

// ---------------- prep: w1t[n][k]=bf16(w1[k][n]) (zero-pad k>=868);
//                  ewt[n][k]=bf16(enr_w[k][n]) (zero-pad to 128x128) ----------
__global__ void prep_kernel(const float* __restrict__ w1, const float* __restrict__ enr_w,
                            unsigned short* __restrict__ w1t, unsigned short* __restrict__ ewt) {
    int i = blockIdx.x * 256 + threadIdx.x;
    if (i < W_ * KP_) {
        int n = i / KP_;
        int k = i - n * KP_;
        w1t[i] = (k < D_ + NF_) ? f2bf(w1[(size_t)k * W_ + n]) : (unsigned short)0;
    }
    int j = i - W_ * KP_;
    if (j >= 0 && j < NFP_ * NFP_) {
        int n = j >> 7, k = j & 127;
        ewt[j] = (n < NF_ && k < NF_) ? f2bf(enr_w[k * NF_ + n]) : (unsigned short)0;
    }
}

// ---------------- valid compaction: gidx[b][p] = src l of p-th valid token ----
__global__ void compact_kernel(const int* __restrict__ valid, int* __restrict__ gidx) {
    __shared__ int s[L_];
    int b = blockIdx.x, t = threadIdx.x; // 512 threads
    int v = valid[b * L_ + t];
    s[t] = v;
    __syncthreads();
    for (int off = 1; off < L_; off <<= 1) {
        int x = (t >= off) ? s[t - off] : 0;
        __syncthreads();
        s[t] += x;
        __syncthreads();
    }
    int inc = s[t];
    gidx[b * L_ + t] = -1;
    __syncthreads();
    if (v) gidx[b * L_ + inc - 1] = t;
}

// ---------------- cls head -----------------------------------------------------
__global__ void cls_kernel(const float* __restrict__ seq, const float* __restrict__ cls_w,
                           const float* __restrict__ cls_b, float* __restrict__ out) {
    int b = blockIdx.x;
    int t = threadIdx.x; // 64 = 1 wave
    const float* row = seq + (size_t)b * L_ * D_;
    float a0 = 0.f, a1 = 0.f;
    for (int d = t; d < D_; d += 64) {
        float x = row[d];
        a0 += x * cls_w[d * CLS_ + 0];
        a1 += x * cls_w[d * CLS_ + 1];
    }
    for (int off = 32; off; off >>= 1) {
        a0 += __shfl_down(a0, off);
        a1 += __shfl_down(a1, off);
    }
    if (t == 0) {
        out[b * CLS_ + 0] = a0 + cls_b[0];
        out[b * CLS_ + 1] = a1 + cls_b[1];
    }
}

// ---------------- enrichment as bf16 MFMA GEMM: enr16 = bf16(relu(feat@enr_w+b))
// M=32768 (BM=32/block), N=128 (full), K=128. 256 thr = 4 waves, wave tile 32x32.
__global__ __launch_bounds__(256, 4)
void enrich_gemm(const float* __restrict__ feat, const unsigned short* __restrict__ ewt,
                 const float* __restrict__ eb, unsigned short* __restrict__ enr16) {
    __shared__ unsigned short As[32 * 40];      // [m][k], stride 40 (pad)
    __shared__ unsigned short Bs[NFP_ * 32];    // [n][k], stride 32 (8 KB)

    const int tid  = threadIdx.x;
    const int lane = tid & 63;
    const int wv   = tid >> 6;
    const int row0 = blockIdx.x * 32;

    const int am = tid >> 3;              // 0..31
    const int ak = (tid & 7) * 4;         // 0..28
    const float* frow = feat + (size_t)(row0 + am) * NF_;

    const int bn = lane >> 2;             // 0..15
    const int bc = (lane & 3) ^ (bn & 3); // XOR-swizzled chunk

    f32x4 acc[2][2];
    const f32x4 zz = {0.f, 0.f, 0.f, 0.f};
    acc[0][0] = zz; acc[0][1] = zz; acc[1][0] = zz; acc[1][1] = zz;

    const int fl = lane & 15;
    const int fq = lane >> 4;
    const int sw = fq ^ (fl & 3);

#pragma unroll 1
    for (int kt = 0; kt < 4; ++kt) {
        const int k0 = kt * 32;
        __syncthreads();
        // stage A (fp32 -> bf16)
        {
            unsigned int u0, u1;
            int k = k0 + ak;
            if (k < NF_) {
                float4 v = *(const float4*)(frow + k);
                u0 = (unsigned int)f2bf(v.x) | ((unsigned int)f2bf(v.y) << 16);
                u1 = (unsigned int)f2bf(v.z) | ((unsigned int)f2bf(v.w) << 16);
            } else { u0 = 0u; u1 = 0u; }
            *(unsigned int*)&As[am * 40 + ak]     = u0;
            *(unsigned int*)&As[am * 40 + ak + 2] = u1;
        }
        // stage B via global_load_lds (wave handles 32 rows = 2 iters of 16)
#pragma unroll
        for (int it = 0; it < 2; ++it) {
            int nr0 = wv * 32 + it * 16;
            const unsigned short* gp = ewt + (size_t)(nr0 + bn) * NFP_ + k0 + bc * 8;
            gload_lds16(gp, &Bs[nr0 * 32]);
        }
        __syncthreads();
        bf16x8 a0 = *(const bf16x8*)&As[fl * 40 + fq * 8];
        bf16x8 a1 = *(const bf16x8*)&As[(16 + fl) * 40 + fq * 8];
#pragma unroll
        for (int nt = 0; nt < 2; ++nt) {
            bf16x8 bfr = *(const bf16x8*)&Bs[(wv * 32 + nt * 16 + fl) * 32 + sw * 8];
            acc[0][nt] = __builtin_amdgcn_mfma_f32_16x16x32_bf16(a0, bfr, acc[0][nt], 0, 0, 0);
            acc[1][nt] = __builtin_amdgcn_mfma_f32_16x16x32_bf16(a1, bfr, acc[1][nt], 0, 0, 0);
        }
    }
    // epilogue: relu + bias, store bf16
#pragma unroll
    for (int nt = 0; nt < 2; ++nt) {
        int n = wv * 32 + nt * 16 + fl;
        float bias = (n < NF_) ? eb[n] : 0.f;
#pragma unroll
        for (int mt = 0; mt < 2; ++mt)
#pragma unroll
            for (int r = 0; r < 4; ++r) {
                float x = acc[mt][nt][r] + bias;
                x = x > 0.f ? x : 0.f;
                int m = row0 + mt * 16 + fq * 4 + r;
                enr16[(size_t)m * NFP_ + n] = f2bf(x);
            }
    }
}

// ---------------- main GEMM: tag = relu(A@w1+b1)@w2 + b2, A gathered bf16 ------
// BM=32, BN=768 (full N -> complete tag row per block), BK=32, 28 K-steps.
// 256 thr = 4 waves; wave tile 32(m) x 192(n) = 2x12 16x16x32 MFMA tiles.
__global__ __launch_bounds__(256, 3)
void main_gemm(const float* __restrict__ seq, const int* __restrict__ gidx,
               const unsigned short* __restrict__ enr16, const unsigned short* __restrict__ w1t,
               const float* __restrict__ b1, const float* __restrict__ w2,
               const float* __restrict__ b2, float* __restrict__ tag) {
    __shared__ unsigned short As[32 * 40];     // [m][k] stride 40 -> 2-way-free b128 reads
    __shared__ unsigned short Bs[W_ * 32];     // [n][k] stride 32, XOR-swizzled 16B chunks (48 KB)
    __shared__ float tagbuf[32 * TOK_];

    const int tid  = threadIdx.x;
    const int lane = tid & 63;
    const int wv   = tid >> 6;
    const int row0 = blockIdx.x * 32;

    if (tid < 32 * TOK_) tagbuf[tid] = b2[tid % TOK_];

    // A staging ids: thread -> (m = tid>>3, 4 k's at ak)
    const int am = tid >> 3;
    const int ak = (tid & 7) * 4;
    const int row = row0 + am;
    const int bb = row >> 9;
    const int g  = gidx[row];
    const float amul = (g >= 0) ? 1.f : 0.f;
    const float* seqrow = seq + ((size_t)(bb << 9) + (g >= 0 ? g : 0)) * D_;
    const unsigned short* enrrow = enr16 + (size_t)row * NFP_;

    // B staging ids
    const int bn = lane >> 2;
    const int bc = (lane & 3) ^ (bn & 3);

    f32x4 acc[2][12];
    const f32x4 zz = {0.f, 0.f, 0.f, 0.f};
#pragma unroll
    for (int i = 0; i < 2; ++i)
#pragma unroll
        for (int j = 0; j < 12; ++j) acc[i][j] = zz;

    const int fl = lane & 15;
    const int fq = lane >> 4;
    const int sw = fq ^ (fl & 3);

#pragma unroll 1
    for (int kt = 0; kt < 28; ++kt) {
        const int k0 = kt * 32;
        __syncthreads();
        // ---- stage A: seq (gathered, fp32->bf16) or enriched (bf16 copy) ----
        unsigned int u0, u1;
        if (k0 < D_) {
            float4 v = *(const float4*)(seqrow + k0 + ak);
            u0 = (unsigned int)f2bf(v.x * amul) | ((unsigned int)f2bf(v.y * amul) << 16);
            u1 = (unsigned int)f2bf(v.z * amul) | ((unsigned int)f2bf(v.w * amul) << 16);
        } else {
            uint2 e = *(const uint2*)(enrrow + (k0 - D_) + ak);
            u0 = e.x; u1 = e.y;
        }
        *(unsigned int*)&As[am * 40 + ak]     = u0;
        *(unsigned int*)&As[am * 40 + ak + 2] = u1;
        // ---- stage B: wave stages rows [wv*192, +192) = 12 iters of 16 rows ----
#pragma unroll
        for (int it = 0; it < 12; ++it) {
            int nr0 = wv * 192 + it * 16;
            const unsigned short* gp = w1t + (size_t)(nr0 + bn) * KP_ + k0 + bc * 8;
            gload_lds16(gp, &Bs[nr0 * 32]);
        }
        __syncthreads();
        // ---- compute: 24 MFMA ----
        bf16x8 a0 = *(const bf16x8*)&As[fl * 40 + fq * 8];
        bf16x8 a1 = *(const bf16x8*)&As[(16 + fl) * 40 + fq * 8];
#pragma unroll
        for (int nt = 0; nt < 12; ++nt) {
            bf16x8 bfr = *(const bf16x8*)&Bs[(wv * 192 + nt * 16 + fl) * 32 + sw * 8];
            acc[0][nt] = __builtin_amdgcn_mfma_f32_16x16x32_bf16(a0, bfr, acc[0][nt], 0, 0, 0);
            acc[1][nt] = __builtin_amdgcn_mfma_f32_16x16x32_bf16(a1, bfr, acc[1][nt], 0, 0, 0);
        }
    }

    // ---- epilogue: h = relu(acc + b1); tag partial = h @ w2; reduce ----
    float b1v[12], w2v[12][TOK_];
#pragma unroll
    for (int nt = 0; nt < 12; ++nt) {
        int n = wv * 192 + nt * 16 + fl;
        b1v[nt] = b1[n];
#pragma unroll
        for (int t = 0; t < TOK_; ++t) w2v[nt][t] = w2[n * TOK_ + t];
    }
#pragma unroll
    for (int mt = 0; mt < 2; ++mt)
#pragma unroll
        for (int r = 0; r < 4; ++r) {
            float h[12];
#pragma unroll
            for (int nt = 0; nt < 12; ++nt) {
                float x = acc[mt][nt][r] + b1v[nt];
                h[nt] = x > 0.f ? x : 0.f;
            }
            float s[TOK_] = {0.f, 0.f, 0.f};
#pragma unroll
            for (int nt = 0; nt < 12; ++nt)
#pragma unroll
                for (int t = 0; t < TOK_; ++t) s[t] += h[nt] * w2v[nt][t];
#pragma unroll
            for (int off = 8; off; off >>= 1)
#pragma unroll
                for (int t = 0; t < TOK_; ++t) s[t] += __shfl_down(s[t], off, 16);
            if (fl == 0) {
                int m = mt * 16 + fq * 4 + r;
#pragma unroll
                for (int t = 0; t < TOK_; ++t) atomicAdd(&tagbuf[m * TOK_ + t], s[t]);
            }
        }
    __syncthreads();
    if (tid < 32 * TOK_) tag[(size_t)row0 * TOK_ + tid] = tagbuf[tid];
}

extern "C" void kernel_launch(void* const* d_in, const int* in_sizes, int n_in,
                              void* d_out, int out_size, void* d_ws, size_t ws_size,
                              hipStream_t stream) {
    const float* seq   = (const float*)d_in[0];
    const float* feat  = (const float*)d_in[1];
    const int*   valid = (const int*)d_in[2];
    const float* enr_w = (const float*)d_in[3];
    const float* enr_b = (const float*)d_in[4];
    const float* w1    = (const float*)d_in[5];
    const float* b1    = (const float*)d_in[6];
    const float* w2    = (const float*)d_in[7];
    const float* b2    = (const float*)d_in[8];
    const float* cls_w = (const float*)d_in[9];
    const float* cls_b = (const float*)d_in[10];

    float* out = (float*)d_out;
    float* cls_out = out;                  // [64,2]
    float* tag_out = out + B_ * CLS_;      // [32768,3]

    // ws layout (all 16B aligned): w1t | ewt | enr16 | gidx  (~9.9 MB)
    unsigned short* w1t   = (unsigned short*)d_ws;                         // 768*896
    unsigned short* ewt   = w1t + (size_t)W_ * KP_;                        // 128*128
    unsigned short* enr16 = ewt + (size_t)NFP_ * NFP_;                     // 32768*128
    int*            gidx  = (int*)(enr16 + (size_t)MTOT_ * NFP_);          // 32768

    prep_kernel<<<(W_ * KP_ + NFP_ * NFP_ + 255) / 256, 256, 0, stream>>>(w1, enr_w, w1t, ewt);
    compact_kernel<<<B_, L_, 0, stream>>>(valid, gidx);
    cls_kernel<<<B_, 64, 0, stream>>>(seq, cls_w, cls_b, cls_out);
    enrich_gemm<<<MTOT_ / 32, 256, 0, stream>>>(feat, ewt, enr_b, enr16);
    main_gemm<<<MTOT_ / 32, 256, 0, stream>>>(seq, gidx, enr16, w1t, b1, w2, b2, tag_out);
}

// Round 5
// 250.522 us; speedup vs baseline: 2.9696x; 1.1922x over previous
//
#include <hip/hip_runtime.h>
#include <hip/hip_bf16.h>

#define B_    64
#define L_    512
#define D_    768
#define NF_   100
#define W_    768
#define TOK_  3
#define CLS_  2
#define MTOT_ (B_ * L_)   // 32768
#define KP_   896         // padded K (768 seq + 128 padded enr)
#define NFP_  128         // padded NF

typedef __attribute__((ext_vector_type(8))) short  bf16x8;
typedef __attribute__((ext_vector_type(4))) float  f32x4;

__device__ __forceinline__ unsigned short f2bf(float f) {
    union { float f; unsigned int u; } v; v.f = f;
    unsigned int u = v.u;
    u += 0x7fffu + ((u >> 16) & 1u);   // RNE
    return (unsigned short)(u >> 16);
}

__device__ __forceinline__ unsigned int pk2(float x, float y) {
    __hip_bfloat162 h = __float22bfloat162_rn(make_float2(x, y)); // v_cvt_pk_bf16_f32 on gfx950
    return *(unsigned int*)&h;
}

typedef __attribute__((address_space(3))) unsigned int        lds_uint;
typedef const __attribute__((address_space(1))) unsigned int  gbl_uint;

__device__ __forceinline__ void gload_lds16(const void* gp, void* lp) {
    __builtin_amdgcn_global_load_lds((gbl_uint*)gp, (lds_uint*)lp, 16, 0, 0);
}

// ---------------- prep: w1t[n][k] = bf16(w1[k][n]), coalesced via LDS transpose --
__global__ void prep_w1t(const float* __restrict__ w1, unsigned short* __restrict__ w1t) {
    __shared__ unsigned short tile[64][72];   // [n-local][k-local], pad 72
    const int k0 = blockIdx.x * 64, n0 = blockIdx.y * 64;
    const int t = threadIdx.x;
    const int kr = t >> 2, cq = t & 3;
    const int k = k0 + kr;
    const float* src = w1 + (size_t)k * W_ + n0 + cq * 16;
    const bool ok = k < (D_ + NF_);
#pragma unroll
    for (int j = 0; j < 4; ++j) {
        float4 v = ok ? *(const float4*)(src + j * 4) : make_float4(0.f, 0.f, 0.f, 0.f);
        int nl = cq * 16 + j * 4;
        tile[nl + 0][kr] = f2bf(v.x);
        tile[nl + 1][kr] = f2bf(v.y);
        tile[nl + 2][kr] = f2bf(v.z);
        tile[nl + 3][kr] = f2bf(v.w);
    }
    __syncthreads();
    const int nr = t >> 2, kq = t & 3;
    uint4 a = *(const uint4*)&tile[nr][kq * 16];
    uint4 b = *(const uint4*)&tile[nr][kq * 16 + 8];
    unsigned short* dst = w1t + (size_t)(n0 + nr) * KP_ + k0 + kq * 16;
    *(uint4*)dst = a;
    *(uint4*)(dst + 8) = b;
}

// ---------------- aux: compact | cls | tag=b2 init | ewt transpose | zrow --------
__global__ void aux_kernel(const int* __restrict__ valid, int* __restrict__ gidx,
                           const float* __restrict__ seq, const float* __restrict__ cls_w,
                           const float* __restrict__ cls_b, float* __restrict__ cls_out,
                           const float* __restrict__ b2, float* __restrict__ tag,
                           const float* __restrict__ enr_w, unsigned short* __restrict__ ewt,
                           float* __restrict__ zrow) {
    const int bx = blockIdx.x, tid = threadIdx.x;
    if (bx < 64) {                       // ---- valid compaction (512 thr) ----
        __shared__ int s[L_];
        int v = valid[bx * L_ + tid];
        s[tid] = v;
        __syncthreads();
        for (int off = 1; off < L_; off <<= 1) {
            int x = (tid >= off) ? s[tid - off] : 0;
            __syncthreads();
            s[tid] += x;
            __syncthreads();
        }
        int inc = s[tid];
        gidx[bx * L_ + tid] = -1;
        __syncthreads();
        if (v) gidx[bx * L_ + inc - 1] = tid;
    } else if (bx < 128) {               // ---- cls head ----
        const int b = bx - 64;
        __shared__ float r0[8], r1[8];
        const float* row = seq + (size_t)b * L_ * D_;
        float a0 = 0.f, a1 = 0.f;
        for (int d = tid; d < D_; d += 512) {
            float x = row[d];
            a0 += x * cls_w[d * CLS_ + 0];
            a1 += x * cls_w[d * CLS_ + 1];
        }
        for (int off = 32; off; off >>= 1) {
            a0 += __shfl_down(a0, off);
            a1 += __shfl_down(a1, off);
        }
        if ((tid & 63) == 0) { r0[tid >> 6] = a0; r1[tid >> 6] = a1; }
        __syncthreads();
        if (tid == 0) {
            float x0 = 0.f, x1 = 0.f;
            for (int i = 0; i < 8; ++i) { x0 += r0[i]; x1 += r1[i]; }
            cls_out[b * CLS_ + 0] = x0 + cls_b[0];
            cls_out[b * CLS_ + 1] = x1 + cls_b[1];
        }
    } else if (bx < 320) {               // ---- tag init to b2 ----
        int i = (bx - 128) * 512 + tid;  // < 98304 exactly
        tag[i] = b2[i % TOK_];
    } else if (bx < 352) {               // ---- ewt transpose+pad ----
        int j = (bx - 320) * 512 + tid;  // < 16384 exactly
        int n = j >> 7, k = j & 127;
        ewt[j] = (n < NF_ && k < NF_) ? f2bf(enr_w[k * NF_ + n]) : (unsigned short)0;
    } else {                             // ---- zero row for invalid gathers ----
        int i = (bx - 352) * 512 + tid;
        if (i < D_) zrow[i] = 0.f;
    }
}

// ---------------- enrichment GEMM: enr16 = bf16(relu(feat@enr_w+b)), N=K=128 ----
__global__ __launch_bounds__(256, 4)
void enrich_gemm(const float* __restrict__ feat, const unsigned short* __restrict__ ewt,
                 const float* __restrict__ eb, unsigned short* __restrict__ enr16) {
    __shared__ unsigned short As[32 * 40];
    __shared__ unsigned short Bs[NFP_ * 32];

    const int tid  = threadIdx.x;
    const int lane = tid & 63;
    const int wv   = tid >> 6;
    const int row0 = blockIdx.x * 32;

    const int am = tid >> 3;
    const int ak = (tid & 7) * 4;
    const float* frow = feat + (size_t)(row0 + am) * NF_;

    const int bn = lane >> 2;
    const int bc = (lane & 3) ^ (bn & 3);

    f32x4 acc[2][2];
    const f32x4 zz = {0.f, 0.f, 0.f, 0.f};
    acc[0][0] = zz; acc[0][1] = zz; acc[1][0] = zz; acc[1][1] = zz;

    const int fl = lane & 15;
    const int fq = lane >> 4;
    const int sw = fq ^ (fl & 3);

#pragma unroll 1
    for (int kt = 0; kt < 4; ++kt) {
        const int k0 = kt * 32;
        __syncthreads();
        {
            unsigned int u0, u1;
            int k = k0 + ak;
            if (k < NF_) {
                float4 v = *(const float4*)(frow + k);
                u0 = pk2(v.x, v.y);
                u1 = pk2(v.z, v.w);
            } else { u0 = 0u; u1 = 0u; }
            *(unsigned int*)&As[am * 40 + ak]     = u0;
            *(unsigned int*)&As[am * 40 + ak + 2] = u1;
        }
#pragma unroll
        for (int it = 0; it < 2; ++it) {
            int nr0 = wv * 32 + it * 16;
            gload_lds16(ewt + (size_t)(nr0 + bn) * NFP_ + k0 + bc * 8, &Bs[nr0 * 32]);
        }
        __syncthreads();
        bf16x8 a0 = *(const bf16x8*)&As[fl * 40 + fq * 8];
        bf16x8 a1 = *(const bf16x8*)&As[(16 + fl) * 40 + fq * 8];
#pragma unroll
        for (int nt = 0; nt < 2; ++nt) {
            bf16x8 bfr = *(const bf16x8*)&Bs[(wv * 32 + nt * 16 + fl) * 32 + sw * 8];
            acc[0][nt] = __builtin_amdgcn_mfma_f32_16x16x32_bf16(a0, bfr, acc[0][nt], 0, 0, 0);
            acc[1][nt] = __builtin_amdgcn_mfma_f32_16x16x32_bf16(a1, bfr, acc[1][nt], 0, 0, 0);
        }
    }
#pragma unroll
    for (int nt = 0; nt < 2; ++nt) {
        int n = wv * 32 + nt * 16 + fl;
        float bias = (n < NF_) ? eb[n] : 0.f;
#pragma unroll
        for (int mt = 0; mt < 2; ++mt)
#pragma unroll
            for (int r = 0; r < 4; ++r) {
                float x = acc[mt][nt][r] + bias;
                x = x > 0.f ? x : 0.f;
                int m = row0 + mt * 16 + fq * 4 + r;
                enr16[(size_t)m * NFP_ + n] = f2bf(x);
            }
    }
}

// ---------------- main GEMM: BM=128, BN=192, BK=64, 4 waves of 64x96 ------------
#define BM 128
#define BN 192

__global__ __launch_bounds__(256, 2)
void main_gemm(const float* __restrict__ seq, const int* __restrict__ gidx,
               const unsigned short* __restrict__ enr16, const unsigned short* __restrict__ w1t,
               const float* __restrict__ zrow,
               const float* __restrict__ b1, const float* __restrict__ w2,
               float* __restrict__ tag) {
    __shared__ unsigned short As[2][BM * 40];   // panel ks: k in [ks*32, +32), stride 40
    __shared__ unsigned short Bs[2][BN * 32];   // panel ks: [n][32k], XOR-swizzled 16B chunks
    __shared__ float tagbuf[BM * TOK_];

    const int tid  = threadIdx.x;
    const int lane = tid & 63;
    const int wv   = tid >> 6;
    const int wvm  = wv >> 1, wvn = wv & 1;
    const int nblk = blockIdx.x & 3;            // n fastest: 4 siblings share A in L2
    const int mblk = blockIdx.x >> 2;
    const int row0 = mblk * BM;
    const int n0   = nblk * BN;

    for (int i = tid; i < BM * TOK_; i += 256) tagbuf[i] = 0.f;

    // A staging: thread -> (row am, panel aq), 32 halfwords each
    const int am = tid >> 1;
    const int aq = tid & 1;
    const int row = row0 + am;
    const int g = gidx[row];
    const float* seqrow = (g >= 0) ? (seq + (((size_t)(row >> 9) << 9) + g) * D_) : zrow;
    const unsigned short* enrrow = enr16 + (size_t)row * NFP_;

    // B staging lane ids
    const int bn = lane >> 2;
    const int bc = (lane & 3) ^ (bn & 3);

    f32x4 acc[4][6];
    const f32x4 zz = {0.f, 0.f, 0.f, 0.f};
#pragma unroll
    for (int i = 0; i < 4; ++i)
#pragma unroll
        for (int j = 0; j < 6; ++j) acc[i][j] = zz;

    const int fl = lane & 15;
    const int fq = lane >> 4;
    const int sw = fq ^ (fl & 3);

#pragma unroll 1
    for (int kt = 0; kt < 14; ++kt) {
        const int k0 = kt * 64;
        __syncthreads();
        // ---- B DMA first (fire async global->LDS) ----
#pragma unroll
        for (int h = 0; h < 2; ++h)
#pragma unroll
            for (int it = 0; it < 3; ++it) {
                int nr0 = wv * 48 + it * 16;
                gload_lds16(w1t + (size_t)(n0 + nr0 + bn) * KP_ + k0 + h * 32 + bc * 8,
                            &Bs[h][nr0 * 32]);
            }
        // ---- A stage: 32 floats -> 32 bf16 (or bf16 copy from enr16) ----
        uint4 w[4];
        if (k0 < D_) {
            const float* p = seqrow + k0 + aq * 32;
#pragma unroll
            for (int j = 0; j < 4; ++j) {
                float4 v0 = *(const float4*)(p + j * 8);
                float4 v1 = *(const float4*)(p + j * 8 + 4);
                w[j].x = pk2(v0.x, v0.y); w[j].y = pk2(v0.z, v0.w);
                w[j].z = pk2(v1.x, v1.y); w[j].w = pk2(v1.z, v1.w);
            }
        } else {
            const unsigned short* p = enrrow + (k0 - D_) + aq * 32;
#pragma unroll
            for (int j = 0; j < 4; ++j) w[j] = *(const uint4*)(p + j * 8);
        }
        {
            unsigned short* dst = &As[aq][am * 40];
#pragma unroll
            for (int j = 0; j < 4; ++j) *(uint4*)(dst + j * 8) = w[j];
        }
        __syncthreads();
        // ---- compute: 2 k-steps x 24 MFMA ----
#pragma unroll
        for (int ks = 0; ks < 2; ++ks) {
            bf16x8 af[4], bfr[6];
#pragma unroll
            for (int mt = 0; mt < 4; ++mt)
                af[mt] = *(const bf16x8*)&As[ks][(wvm * 64 + mt * 16 + fl) * 40 + fq * 8];
#pragma unroll
            for (int nt = 0; nt < 6; ++nt)
                bfr[nt] = *(const bf16x8*)&Bs[ks][(wvn * 96 + nt * 16 + fl) * 32 + sw * 8];
#pragma unroll
            for (int mt = 0; mt < 4; ++mt)
#pragma unroll
                for (int nt = 0; nt < 6; ++nt)
                    acc[mt][nt] = __builtin_amdgcn_mfma_f32_16x16x32_bf16(af[mt], bfr[nt], acc[mt][nt], 0, 0, 0);
        }
    }

    // ---- epilogue: h = relu(acc+b1); tag partial = h@w2; LDS then global atomics
    float b1v[6], w2v[6][TOK_];
#pragma unroll
    for (int nt = 0; nt < 6; ++nt) {
        int n = n0 + wvn * 96 + nt * 16 + fl;
        b1v[nt] = b1[n];
#pragma unroll
        for (int t = 0; t < TOK_; ++t) w2v[nt][t] = w2[n * TOK_ + t];
    }
#pragma unroll
    for (int mt = 0; mt < 4; ++mt)
#pragma unroll
        for (int r = 0; r < 4; ++r) {
            float s[TOK_] = {0.f, 0.f, 0.f};
#pragma unroll
            for (int nt = 0; nt < 6; ++nt) {
                float h = acc[mt][nt][r] + b1v[nt];
                h = h > 0.f ? h : 0.f;
#pragma unroll
                for (int t = 0; t < TOK_; ++t) s[t] += h * w2v[nt][t];
            }
#pragma unroll
            for (int off = 8; off; off >>= 1)
#pragma unroll
                for (int t = 0; t < TOK_; ++t) s[t] += __shfl_down(s[t], off, 16);
            if (fl == 0) {
                int m = wvm * 64 + mt * 16 + fq * 4 + r;
#pragma unroll
                for (int t = 0; t < TOK_; ++t) atomicAdd(&tagbuf[m * TOK_ + t], s[t]);
            }
        }
    __syncthreads();
    for (int i = tid; i < BM * TOK_; i += 256)
        atomicAdd(&tag[(size_t)row0 * TOK_ + i], tagbuf[i]);
}

extern "C" void kernel_launch(void* const* d_in, const int* in_sizes, int n_in,
                              void* d_out, int out_size, void* d_ws, size_t ws_size,
                              hipStream_t stream) {
    const float* seq   = (const float*)d_in[0];
    const float* feat  = (const float*)d_in[1];
    const int*   valid = (const int*)d_in[2];
    const float* enr_w = (const float*)d_in[3];
    const float* enr_b = (const float*)d_in[4];
    const float* w1    = (const float*)d_in[5];
    const float* b1    = (const float*)d_in[6];
    const float* w2    = (const float*)d_in[7];
    const float* b2    = (const float*)d_in[8];
    const float* cls_w = (const float*)d_in[9];
    const float* cls_b = (const float*)d_in[10];

    float* out = (float*)d_out;
    float* cls_out = out;                  // [64,2]
    float* tag_out = out + B_ * CLS_;      // [32768,3]

    // ws: w1t | ewt | enr16 | gidx | zrow  (~9.9 MB, 16B-aligned chunks)
    unsigned short* w1t   = (unsigned short*)d_ws;                 // 768*896*2 B
    unsigned short* ewt   = w1t + (size_t)W_ * KP_;                // 128*128*2 B
    unsigned short* enr16 = ewt + (size_t)NFP_ * NFP_;             // 32768*128*2 B
    int*            gidx  = (int*)(enr16 + (size_t)MTOT_ * NFP_);  // 32768*4 B
    float*          zrow  = (float*)(gidx + MTOT_);                // 768*4 B

    prep_w1t<<<dim3(KP_ / 64, W_ / 64), 256, 0, stream>>>(w1, w1t);
    aux_kernel<<<354, 512, 0, stream>>>(valid, gidx, seq, cls_w, cls_b, cls_out,
                                        b2, tag_out, enr_w, ewt, zrow);
    enrich_gemm<<<MTOT_ / 32, 256, 0, stream>>>(feat, ewt, enr_b, enr16);
    main_gemm<<<(MTOT_ / BM) * 4, 256, 0, stream>>>(seq, gidx, enr16, w1t, zrow, b1, w2, tag_out);
}